// Round 1
// baseline (1784.010 us; speedup 1.0000x reference)
//
#include <hip/hip_runtime.h>

#define NTOT 4096
#define CH 256
#define SCALE 0.0390625f   // 1/(256*0.1)
#define LAM 0.001f

__device__ __forceinline__ float wave_max64(float v) {
  #pragma unroll
  for (int o = 32; o; o >>= 1) v = fmaxf(v, __shfl_down(v, o, 64));
  return v;
}
__device__ __forceinline__ float wave_sum64(float v) {
  #pragma unroll
  for (int o = 32; o; o >>= 1) v += __shfl_down(v, o, 64);
  return v;
}

// out[row] = ||x_row||^2 ; x is [rows][CH] f32, one wave per row
__global__ __launch_bounds__(64) void row_norms_k(const float* __restrict__ x,
                                                  float* __restrict__ out) {
  const int row = blockIdx.x;
  const float4 v = *reinterpret_cast<const float4*>(x + (size_t)row * CH + threadIdx.x * 4);
  float s = v.x * v.x + v.y * v.y + v.z * v.z + v.w * v.w;
  s = wave_sum64(s);
  if (threadIdx.x == 0) out[row] = s;
}

// C[r][j] = sum_k A[r][k] * B[j][k]
// A: [R][CH] (ld CH), B: [NTOT][CH] (ld CH), C: [R][NTOT]
// 64x64 output tile per block, K-chunks of 64, 256 threads, 4x4 per thread.
// LDS pad 68: A-reads and B-reads both max 2-way bank aliasing (free).
__global__ __launch_bounds__(256) void gemm_nt_k(const float* __restrict__ A,
                                                 const float* __restrict__ B,
                                                 float* __restrict__ Cc) {
  __shared__ __align__(16) float As[64][68];
  __shared__ __align__(16) float Bs[64][68];
  const int tid = threadIdx.x;
  const int tx = tid & 15;   // N direction (cols tx + 16j)
  const int ty = tid >> 4;   // M direction (rows ty*4 + i)
  const int bm = blockIdx.y * 64;
  const int bn = blockIdx.x * 64;
  float acc[4][4] = {};
  for (int k0 = 0; k0 < CH; k0 += 64) {
    #pragma unroll
    for (int i = tid; i < 1024; i += 256) {
      const int r = i >> 4, c4 = (i & 15) * 4;
      *reinterpret_cast<float4*>(&As[r][c4]) =
          *reinterpret_cast<const float4*>(A + (size_t)(bm + r) * CH + k0 + c4);
      *reinterpret_cast<float4*>(&Bs[r][c4]) =
          *reinterpret_cast<const float4*>(B + (size_t)(bn + r) * CH + k0 + c4);
    }
    __syncthreads();
    #pragma unroll
    for (int kk = 0; kk < 64; kk += 4) {
      float4 a4[4], b4[4];
      #pragma unroll
      for (int i = 0; i < 4; i++) a4[i] = *reinterpret_cast<const float4*>(&As[ty * 4 + i][kk]);
      #pragma unroll
      for (int j = 0; j < 4; j++) b4[j] = *reinterpret_cast<const float4*>(&Bs[tx + 16 * j][kk]);
      #pragma unroll
      for (int i = 0; i < 4; i++)
        #pragma unroll
        for (int j = 0; j < 4; j++)
          acc[i][j] += a4[i].x * b4[j].x + a4[i].y * b4[j].y +
                       a4[i].z * b4[j].z + a4[i].w * b4[j].w;
    }
    __syncthreads();
  }
  #pragma unroll
  for (int i = 0; i < 4; i++)
    #pragma unroll
    for (int j = 0; j < 4; j++)
      Cc[(size_t)(bm + ty * 4 + i) * NTOT + bn + tx + 16 * j] = acc[i][j];
}

// Q[r][c] = (sum_j E[r][j] * B[j][c]) / dn[r]
// E: [R][NTOT] (unnormalized softmax weights), B: [NTOT][CH], Q: [R][CH]
__global__ __launch_bounds__(256) void gemm_nn_k(const float* __restrict__ E,
                                                 const float* __restrict__ B,
                                                 const float* __restrict__ dn,
                                                 float* __restrict__ Q) {
  __shared__ __align__(16) float Es[64][68];
  __shared__ __align__(16) float Bs[64][68];
  const int tid = threadIdx.x;
  const int tx = tid & 15;
  const int ty = tid >> 4;
  const int bm = blockIdx.y * 64;
  const int bn = blockIdx.x * 64;
  float acc[4][4] = {};
  for (int k0 = 0; k0 < NTOT; k0 += 64) {
    #pragma unroll
    for (int i = tid; i < 1024; i += 256) {
      const int r = i >> 4, c4 = (i & 15) * 4;
      *reinterpret_cast<float4*>(&Es[r][c4]) =
          *reinterpret_cast<const float4*>(E + (size_t)(bm + r) * NTOT + k0 + c4);
      *reinterpret_cast<float4*>(&Bs[r][c4]) =
          *reinterpret_cast<const float4*>(B + (size_t)(k0 + r) * CH + bn + c4);
    }
    __syncthreads();
    #pragma unroll
    for (int kk = 0; kk < 64; kk += 4) {
      float4 a4[4];
      #pragma unroll
      for (int i = 0; i < 4; i++) a4[i] = *reinterpret_cast<const float4*>(&Es[ty * 4 + i][kk]);
      #pragma unroll
      for (int q = 0; q < 4; q++) {
        float bq[4];
        #pragma unroll
        for (int j = 0; j < 4; j++) bq[j] = Bs[kk + q][tx + 16 * j];
        #pragma unroll
        for (int i = 0; i < 4; i++) {
          const float av = reinterpret_cast<const float*>(&a4[i])[q];
          #pragma unroll
          for (int j = 0; j < 4; j++) acc[i][j] += av * bq[j];
        }
      }
    }
    __syncthreads();
  }
  #pragma unroll
  for (int i = 0; i < 4; i++) {
    const float rd = 1.0f / dn[bm + ty * 4 + i];
    #pragma unroll
    for (int j = 0; j < 4; j++)
      Q[(size_t)(bm + ty * 4 + i) * CH + bn + tx + 16 * j] = acc[i][j] * rd;
  }
}

// Row softmax over logits l_j = (2*S[row][j] - nx[row] - ny[j]) * SCALE.
// Writes UNNORMALIZED exp(l-m) back into S; denom[row] = sum (folded in later).
__global__ __launch_bounds__(256) void softmax_rows_k(float* __restrict__ S,
                                                      const float* __restrict__ nx,
                                                      const float* __restrict__ ny,
                                                      float* __restrict__ denom) {
  const int row = blockIdx.x;
  const int tid = threadIdx.x;
  float* __restrict__ Sr = S + (size_t)row * NTOT;
  const float nxr = nx[row];
  __shared__ float red[4];

  float m = -3.0e38f;
  for (int j = tid * 4; j < NTOT; j += 1024) {
    const float4 s = *reinterpret_cast<const float4*>(Sr + j);
    const float4 y = *reinterpret_cast<const float4*>(ny + j);
    const float l0 = (2.f * s.x - nxr - y.x) * SCALE;
    const float l1 = (2.f * s.y - nxr - y.y) * SCALE;
    const float l2 = (2.f * s.z - nxr - y.z) * SCALE;
    const float l3 = (2.f * s.w - nxr - y.w) * SCALE;
    m = fmaxf(m, fmaxf(fmaxf(l0, l1), fmaxf(l2, l3)));
  }
  m = wave_max64(m);
  if ((tid & 63) == 0) red[tid >> 6] = m;
  __syncthreads();
  m = fmaxf(fmaxf(red[0], red[1]), fmaxf(red[2], red[3]));
  __syncthreads();

  float s0 = 0.f;
  for (int j = tid * 4; j < NTOT; j += 1024) {
    const float4 s = *reinterpret_cast<const float4*>(Sr + j);
    const float4 y = *reinterpret_cast<const float4*>(ny + j);
    float4 e;
    e.x = __expf((2.f * s.x - nxr - y.x) * SCALE - m);
    e.y = __expf((2.f * s.y - nxr - y.y) * SCALE - m);
    e.z = __expf((2.f * s.z - nxr - y.z) * SCALE - m);
    e.w = __expf((2.f * s.w - nxr - y.w) * SCALE - m);
    *reinterpret_cast<float4*>(Sr + j) = e;
    s0 += e.x + e.y + e.z + e.w;
  }
  s0 = wave_sum64(s0);
  if ((tid & 63) == 0) red[tid >> 6] = s0;
  __syncthreads();
  if (tid == 0) denom[row] = red[0] + red[1] + red[2] + red[3];
}

// Second softmax (beta) fused with pred/var/loss-term computation.
// l_j = (2*T[row][j] - nq[row] - nxall[j]) * SCALE
// pred = E[idx], var = E[idx^2]-pred^2; term = (idx[row0+row]-pred)^2/var + LAM*log(var)
__global__ __launch_bounds__(256) void stats_rows_k(const float* __restrict__ T,
                                                    const float* __restrict__ nq,
                                                    const float* __restrict__ nxall,
                                                    const float* __restrict__ idx,
                                                    const int row0,
                                                    float* __restrict__ terms) {
  const int row = blockIdx.x;
  const int tid = threadIdx.x;
  const float* __restrict__ Tr = T + (size_t)row * NTOT;
  const float nqr = nq[row];
  __shared__ float red[12];

  float m = -3.0e38f;
  for (int j = tid * 4; j < NTOT; j += 1024) {
    const float4 t = *reinterpret_cast<const float4*>(Tr + j);
    const float4 y = *reinterpret_cast<const float4*>(nxall + j);
    m = fmaxf(m, fmaxf(fmaxf(2.f * t.x - nqr - y.x, 2.f * t.y - nqr - y.y),
                       fmaxf(2.f * t.z - nqr - y.z, 2.f * t.w - nqr - y.w)));
  }
  m = wave_max64(m);
  if ((tid & 63) == 0) red[tid >> 6] = m;
  __syncthreads();
  m = fmaxf(fmaxf(red[0], red[1]), fmaxf(red[2], red[3])) * SCALE;  // SCALE>0: commutes with max
  __syncthreads();

  float s0 = 0.f, s1 = 0.f, s2 = 0.f;
  for (int j = tid * 4; j < NTOT; j += 1024) {
    const float4 t = *reinterpret_cast<const float4*>(Tr + j);
    const float4 y = *reinterpret_cast<const float4*>(nxall + j);
    const float4 q = *reinterpret_cast<const float4*>(idx + j);
    float w;
    w = __expf((2.f * t.x - nqr - y.x) * SCALE - m); s0 += w; s1 += w * q.x; s2 += w * q.x * q.x;
    w = __expf((2.f * t.y - nqr - y.y) * SCALE - m); s0 += w; s1 += w * q.y; s2 += w * q.y * q.y;
    w = __expf((2.f * t.z - nqr - y.z) * SCALE - m); s0 += w; s1 += w * q.z; s2 += w * q.z * q.z;
    w = __expf((2.f * t.w - nqr - y.w) * SCALE - m); s0 += w; s1 += w * q.w; s2 += w * q.w * q.w;
  }
  s0 = wave_sum64(s0); s1 = wave_sum64(s1); s2 = wave_sum64(s2);
  if ((tid & 63) == 0) { const int w = tid >> 6; red[w] = s0; red[4 + w] = s1; red[8 + w] = s2; }
  __syncthreads();
  if (tid == 0) {
    s0 = red[0] + red[1] + red[2] + red[3];
    s1 = red[4] + red[5] + red[6] + red[7];
    s2 = red[8] + red[9] + red[10] + red[11];
    const float pred = s1 / s0;
    const float var = s2 / s0 - pred * pred;
    const float d = idx[row0 + row] - pred;
    terms[row0 + row] = d * d / var + LAM * logf(var);
  }
}

// Deterministic final sum of 2*NTOT row terms -> scalar loss
__global__ __launch_bounds__(256) void final_reduce_k(const float* __restrict__ terms,
                                                      float* __restrict__ out) {
  float s = 0.f;
  for (int i = threadIdx.x; i < 2 * NTOT; i += 256) s += terms[i];
  __shared__ float red[4];
  s = wave_sum64(s);
  if ((threadIdx.x & 63) == 0) red[threadIdx.x >> 6] = s;
  __syncthreads();
  if (threadIdx.x == 0) out[0] = (red[0] + red[1] + red[2] + red[3]) * (1.0f / (2.0f * NTOT));
}

extern "C" void kernel_launch(void* const* d_in, const int* in_sizes, int n_in,
                              void* d_out, int out_size, void* d_ws, size_t ws_size,
                              hipStream_t stream) {
  const float* a    = (const float*)d_in[0];
  const float* b    = (const float*)d_in[1];
  const float* idxa = (const float*)d_in[2];
  const float* idxb = (const float*)d_in[3];
  float* out = (float*)d_out;
  char* ws = (char*)d_ws;

  // Row-chunk size adapts to available workspace (full chunk needs ~68.1 MB).
  auto need = [](int R) -> size_t {
    return (size_t)R * NTOT * 4 + (size_t)R * CH * 4 + (size_t)NTOT * 8 +
           (size_t)R * 8 + (size_t)2 * NTOT * 4;
  };
  int R = NTOT;
  while (R > 256 && need(R) > ws_size) R >>= 1;

  size_t off = 0;
  float* S     = (float*)(ws + off); off += (size_t)R * NTOT * 4;  // scores / exp-weights / T
  float* Q     = (float*)(ws + off); off += (size_t)R * CH * 4;    // soft_nn chunk
  float* na    = (float*)(ws + off); off += (size_t)NTOT * 4;
  float* nb    = (float*)(ws + off); off += (size_t)NTOT * 4;
  float* nq    = (float*)(ws + off); off += (size_t)R * 4;
  float* dn    = (float*)(ws + off); off += (size_t)R * 4;
  float* terms = (float*)(ws + off);

  row_norms_k<<<NTOT, 64, 0, stream>>>(a, na);
  row_norms_k<<<NTOT, 64, 0, stream>>>(b, nb);

  for (int dir = 0; dir < 2; ++dir) {
    const float* X   = dir ? b : a;      // "emb_a" of this direction
    const float* Y   = dir ? a : b;      // "emb_b" of this direction
    const float* nx  = dir ? nb : na;
    const float* ny  = dir ? na : nb;
    const float* idx = dir ? idxb : idxa;
    float* tbase = terms + dir * NTOT;

    for (int r0 = 0; r0 < NTOT; r0 += R) {
      // S = X_chunk . Y^T
      gemm_nt_k<<<dim3(NTOT / 64, R / 64), 256, 0, stream>>>(X + (size_t)r0 * CH, Y, S);
      // unnormalized row softmax of logits, denom saved
      softmax_rows_k<<<R, 256, 0, stream>>>(S, nx + r0, ny, dn);
      // Q = softmax(S) @ Y  (1/denom folded into epilogue)
      gemm_nn_k<<<dim3(CH / 64, R / 64), 256, 0, stream>>>(S, Y, dn, Q);
      row_norms_k<<<R, 64, 0, stream>>>(Q, nq);
      // T = Q . X^T  (full X, all NTOT cols)
      gemm_nt_k<<<dim3(NTOT / 64, R / 64), 256, 0, stream>>>(Q, X, S);
      // beta softmax + pred/var + loss terms
      stats_rows_k<<<R, 256, 0, stream>>>(S, nq, nx, idx, r0, tbase);
    }
  }
  final_reduce_k<<<1, 256, 0, stream>>>(terms, out);
}

// Round 2
// 242.303 us; speedup vs baseline: 7.3627x; 7.3627x over previous
//
#include <hip/hip_runtime.h>

#define NTOT 4096
#define CH 256
#define SCALE 0.0390625f   // 1/(256*0.1)
#define LAM 0.001f

typedef unsigned short u16;
typedef __attribute__((ext_vector_type(8))) short short8;   // 8 bf16 (4 VGPRs)
typedef __attribute__((ext_vector_type(4))) float floatx4;  // MFMA acc

__device__ __forceinline__ float wave_max64(float v) {
  #pragma unroll
  for (int o = 32; o; o >>= 1) v = fmaxf(v, __shfl_down(v, o, 64));
  return v;
}
__device__ __forceinline__ float wave_sum64(float v) {
  #pragma unroll
  for (int o = 32; o; o >>= 1) v += __shfl_down(v, o, 64);
  return v;
}
__device__ __forceinline__ u16 f2bf(float f) {  // round-to-nearest-even
  unsigned u = __float_as_uint(f);
  u += 0x7fffu + ((u >> 16) & 1u);
  return (u16)(u >> 16);
}
__device__ __forceinline__ float bf2f(u16 h) {
  return __uint_as_float(((unsigned)h) << 16);
}

// f32 -> bf16 for both inputs + row norms of the ROUNDED values (one wave/row).
__global__ __launch_bounds__(64) void cvt_norm_k(const float* __restrict__ a,
                                                 const float* __restrict__ b,
                                                 u16* __restrict__ ab, u16* __restrict__ bb,
                                                 float* __restrict__ na, float* __restrict__ nb) {
  int row = blockIdx.x;
  const float* src; u16* dst; float* nd;
  if (row < NTOT) { src = a; dst = ab; nd = na; }
  else { row -= NTOT; src = b; dst = bb; nd = nb; }
  const float4 v = *reinterpret_cast<const float4*>(src + (size_t)row * CH + threadIdx.x * 4);
  const u16 h0 = f2bf(v.x), h1 = f2bf(v.y), h2 = f2bf(v.z), h3 = f2bf(v.w);
  uint2 st;
  st.x = (unsigned)h0 | ((unsigned)h1 << 16);
  st.y = (unsigned)h2 | ((unsigned)h3 << 16);
  *reinterpret_cast<uint2*>(dst + (size_t)row * CH + threadIdx.x * 4) = st;
  const float f0 = bf2f(h0), f1 = bf2f(h1), f2 = bf2f(h2), f3 = bf2f(h3);
  float s = f0 * f0 + f1 * f1 + f2 * f2 + f3 * f3;
  s = wave_sum64(s);
  if (threadIdx.x == 0) nd[row] = s;
}

// [4096][256] -> [256][4096] bf16 transpose for both inputs (z selects a/b)
__global__ __launch_bounds__(256) void transpose2_k(const u16* __restrict__ ab,
                                                    const u16* __restrict__ bb,
                                                    u16* __restrict__ at, u16* __restrict__ bt) {
  const u16* __restrict__ src = blockIdx.z ? bb : ab;
  u16* __restrict__ dst = blockIdx.z ? bt : at;
  __shared__ u16 t[32][33];
  const int bx = blockIdx.x * 32, by = blockIdx.y * 32;
  const int lx = threadIdx.x & 31, ly = threadIdx.x >> 5;
  #pragma unroll
  for (int i = 0; i < 32; i += 8)
    t[ly + i][lx] = src[(size_t)(by + ly + i) * CH + bx + lx];
  __syncthreads();
  #pragma unroll
  for (int i = 0; i < 32; i += 8)
    dst[(size_t)(bx + ly + i) * NTOT + by + lx] = t[lx][ly + i];
}

// NT bf16 MFMA GEMM: C[i][j] = sum_k A[i][k]*B[j][k]   (both row-major, K contiguous)
// 4 waves as 2x2; wave tile (MF*16)x(NF*16); BK=64; m97 2-barrier structure with
// global_load_lds width-16 staging. grid = (N/BN, M/BM, KSplits); block's K range
// = [z*kchunk, (z+1)*kchunk); output C + z*cstride.
template<int BM, int BN, int MF, int NF>
__global__ __launch_bounds__(256, 2) void gemm_nt_mfma(const u16* __restrict__ A,
                                                       const u16* __restrict__ B,
                                                       float* __restrict__ C,
                                                       int lda, int ldb, int ldc,
                                                       int kchunk, size_t cstride) {
  __shared__ u16 As[BM][64];
  __shared__ u16 Bs[BN][64];
  const int tid = threadIdx.x;
  const int wid = tid >> 6, lane = tid & 63;
  const int bn = blockIdx.x * BN, bm = blockIdx.y * BM;
  const int k0base = blockIdx.z * kchunk;
  C += (size_t)blockIdx.z * cstride;
  const int wr = (wid >> 1) * MF * 16;   // wave row offset in tile
  const int wc = (wid & 1) * NF * 16;    // wave col offset in tile
  const int lr = lane & 15;              // fragment row/col
  const int lk = (lane >> 4) * 8;        // fragment k offset within K=32

  floatx4 acc[MF][NF] = {};

  for (int kk = 0; kk < kchunk; kk += 64) {
    const int k0 = k0base + kk;
    // ---- stage A/B 64-wide K tiles into LDS (linear dest, per-lane global src)
    #pragma unroll
    for (int i = 0; i < BM / 32; ++i) {
      const int lb = (wid + 4 * i) * 1024;            // wave-uniform LDS byte base
      const int r = (lb + lane * 16) >> 7;            // /128 B per row
      const int c = ((lb + lane * 16) & 127) >> 1;    // bf16 col
      __builtin_amdgcn_global_load_lds(
          (const __attribute__((address_space(1))) void*)(A + (size_t)(bm + r) * lda + k0 + c),
          (__attribute__((address_space(3))) void*)((char*)&As[0][0] + lb), 16, 0, 0);
    }
    #pragma unroll
    for (int i = 0; i < BN / 32; ++i) {
      const int lb = (wid + 4 * i) * 1024;
      const int r = (lb + lane * 16) >> 7;
      const int c = ((lb + lane * 16) & 127) >> 1;
      __builtin_amdgcn_global_load_lds(
          (const __attribute__((address_space(1))) void*)(B + (size_t)(bn + r) * ldb + k0 + c),
          (__attribute__((address_space(3))) void*)((char*)&Bs[0][0] + lb), 16, 0, 0);
    }
    __syncthreads();   // drains vmcnt before barrier (compiler-enforced)
    // ---- 2 MFMA K-steps of 32
    #pragma unroll
    for (int ks = 0; ks < 2; ++ks) {
      short8 af[MF], bfr[NF];
      #pragma unroll
      for (int m = 0; m < MF; ++m)
        af[m] = *reinterpret_cast<const short8*>(&As[wr + m * 16 + lr][ks * 32 + lk]);
      #pragma unroll
      for (int n = 0; n < NF; ++n)
        bfr[n] = *reinterpret_cast<const short8*>(&Bs[wc + n * 16 + lr][ks * 32 + lk]);
      #pragma unroll
      for (int m = 0; m < MF; ++m)
        #pragma unroll
        for (int n = 0; n < NF; ++n)
          acc[m][n] = __builtin_amdgcn_mfma_f32_16x16x32_bf16(af[m], bfr[n], acc[m][n], 0, 0, 0);
    }
    __syncthreads();
  }
  // ---- epilogue: D row = (lane>>4)*4 + r, col = lane&15 (m89-verified mapping)
  #pragma unroll
  for (int m = 0; m < MF; ++m) {
    const int row = bm + wr + m * 16 + (lane >> 4) * 4;
    #pragma unroll
    for (int n = 0; n < NF; ++n) {
      const int col = bn + wc + n * 16 + lr;
      #pragma unroll
      for (int r = 0; r < 4; ++r)
        C[(size_t)(row + r) * ldc + col] = acc[m][n][r];
    }
  }
}

// Row softmax of logits l_j = (2*S[row][j] - ny[j])*SCALE (per-row const cancels).
// Writes UNNORMALIZED bf16 weights E; dn[row] = sum of the rounded weights.
__global__ __launch_bounds__(256) void softmax_rows_k(const float* __restrict__ S,
                                                      const float* __restrict__ ny,
                                                      u16* __restrict__ E,
                                                      float* __restrict__ dn) {
  const int row = blockIdx.x, tid = threadIdx.x;
  const float* __restrict__ Sr = S + (size_t)row * NTOT;
  u16* __restrict__ Er = E + (size_t)row * NTOT;
  __shared__ float red[4];
  float m = -3.0e38f;
  for (int j = tid * 4; j < NTOT; j += 1024) {
    const float4 s = *reinterpret_cast<const float4*>(Sr + j);
    const float4 y = *reinterpret_cast<const float4*>(ny + j);
    m = fmaxf(m, fmaxf(fmaxf(2.f * s.x - y.x, 2.f * s.y - y.y),
                       fmaxf(2.f * s.z - y.z, 2.f * s.w - y.w)));
  }
  m = wave_max64(m);
  if ((tid & 63) == 0) red[tid >> 6] = m;
  __syncthreads();
  const float ms = fmaxf(fmaxf(red[0], red[1]), fmaxf(red[2], red[3])) * SCALE;
  __syncthreads();
  float s0 = 0.f;
  for (int j = tid * 4; j < NTOT; j += 1024) {
    const float4 s = *reinterpret_cast<const float4*>(Sr + j);
    const float4 y = *reinterpret_cast<const float4*>(ny + j);
    const u16 h0 = f2bf(__expf((2.f * s.x - y.x) * SCALE - ms));
    const u16 h1 = f2bf(__expf((2.f * s.y - y.y) * SCALE - ms));
    const u16 h2 = f2bf(__expf((2.f * s.z - y.z) * SCALE - ms));
    const u16 h3 = f2bf(__expf((2.f * s.w - y.w) * SCALE - ms));
    uint2 st;
    st.x = (unsigned)h0 | ((unsigned)h1 << 16);
    st.y = (unsigned)h2 | ((unsigned)h3 << 16);
    *reinterpret_cast<uint2*>(Er + j) = st;
    s0 += bf2f(h0) + bf2f(h1) + bf2f(h2) + bf2f(h3);
  }
  s0 = wave_sum64(s0);
  if ((tid & 63) == 0) red[tid >> 6] = s0;
  __syncthreads();
  if (tid == 0) dn[row] = red[0] + red[1] + red[2] + red[3];
}

// Q = (sum of 4 split-K partials) / dn -> bf16. One block per row, thread = col.
__global__ __launch_bounds__(256) void reduce_q_k(const float* __restrict__ Qp,
                                                  const float* __restrict__ dn,
                                                  u16* __restrict__ Qb, int R) {
  const int row = blockIdx.x;
  const float rdn = 1.0f / dn[row];
  const size_t o = (size_t)row * CH + threadIdx.x;
  const size_t st = (size_t)R * CH;
  const float q = (Qp[o] + Qp[o + st] + Qp[o + 2 * st] + Qp[o + 3 * st]) * rdn;
  Qb[o] = f2bf(q);
}

// beta softmax (l_j = (2*T[row][j] - nx[j])*SCALE; per-row ||q||^2 const cancels)
// fused with pred/var/loss-term.
__global__ __launch_bounds__(256) void stats_rows_k(const float* __restrict__ T,
                                                    const float* __restrict__ nx,
                                                    const float* __restrict__ idx,
                                                    const int row0,
                                                    float* __restrict__ terms) {
  const int row = blockIdx.x, tid = threadIdx.x;
  const float* __restrict__ Tr = T + (size_t)row * NTOT;
  __shared__ float red[12];
  float m = -3.0e38f;
  for (int j = tid * 4; j < NTOT; j += 1024) {
    const float4 t = *reinterpret_cast<const float4*>(Tr + j);
    const float4 y = *reinterpret_cast<const float4*>(nx + j);
    m = fmaxf(m, fmaxf(fmaxf(2.f * t.x - y.x, 2.f * t.y - y.y),
                       fmaxf(2.f * t.z - y.z, 2.f * t.w - y.w)));
  }
  m = wave_max64(m);
  if ((tid & 63) == 0) red[tid >> 6] = m;
  __syncthreads();
  const float ms = fmaxf(fmaxf(red[0], red[1]), fmaxf(red[2], red[3])) * SCALE;
  __syncthreads();
  float s0 = 0.f, s1 = 0.f, s2 = 0.f;
  for (int j = tid * 4; j < NTOT; j += 1024) {
    const float4 t = *reinterpret_cast<const float4*>(Tr + j);
    const float4 y = *reinterpret_cast<const float4*>(nx + j);
    const float4 q = *reinterpret_cast<const float4*>(idx + j);
    float w;
    w = __expf((2.f * t.x - y.x) * SCALE - ms); s0 += w; s1 += w * q.x; s2 += w * q.x * q.x;
    w = __expf((2.f * t.y - y.y) * SCALE - ms); s0 += w; s1 += w * q.y; s2 += w * q.y * q.y;
    w = __expf((2.f * t.z - y.z) * SCALE - ms); s0 += w; s1 += w * q.z; s2 += w * q.z * q.z;
    w = __expf((2.f * t.w - y.w) * SCALE - ms); s0 += w; s1 += w * q.w; s2 += w * q.w * q.w;
  }
  s0 = wave_sum64(s0); s1 = wave_sum64(s1); s2 = wave_sum64(s2);
  if ((tid & 63) == 0) { const int w = tid >> 6; red[w] = s0; red[4 + w] = s1; red[8 + w] = s2; }
  __syncthreads();
  if (tid == 0) {
    s0 = red[0] + red[1] + red[2] + red[3];
    s1 = red[4] + red[5] + red[6] + red[7];
    s2 = red[8] + red[9] + red[10] + red[11];
    const float pred = s1 / s0;
    const float var = s2 / s0 - pred * pred;
    const float d = idx[row0 + row] - pred;
    terms[row0 + row] = d * d / var + LAM * logf(var);
  }
}

__global__ __launch_bounds__(256) void final_reduce_k(const float* __restrict__ terms,
                                                      float* __restrict__ out) {
  float s = 0.f;
  for (int i = threadIdx.x; i < 2 * NTOT; i += 256) s += terms[i];
  __shared__ float red[4];
  s = wave_sum64(s);
  if ((threadIdx.x & 63) == 0) red[threadIdx.x >> 6] = s;
  __syncthreads();
  if (threadIdx.x == 0) out[0] = (red[0] + red[1] + red[2] + red[3]) * (1.0f / (2.0f * NTOT));
}

extern "C" void kernel_launch(void* const* d_in, const int* in_sizes, int n_in,
                              void* d_out, int out_size, void* d_ws, size_t ws_size,
                              hipStream_t stream) {
  const float* a    = (const float*)d_in[0];
  const float* b    = (const float*)d_in[1];
  const float* idxa = (const float*)d_in[2];
  const float* idxb = (const float*)d_in[3];
  float* out = (float*)d_out;
  char* ws = (char*)d_ws;

  auto need = [](size_t R) -> size_t {
    return R * NTOT * 4 + R * NTOT * 2 + 4 * R * CH * 4 + R * CH * 2 +
           4 * (size_t)NTOT * CH * 2 + 2 * (size_t)NTOT * 4 + R * 4 + 2 * (size_t)NTOT * 4;
  };
  size_t R = NTOT;                              // R=4096 needs ~128 MB, R=2048 ~68 MB
  while (R > 128 && need(R) > ws_size) R >>= 1;

  size_t off = 0;
  float* S   = (float*)(ws + off); off += R * NTOT * 4;        // scores, reused as T
  u16*   E   = (u16*)(ws + off);   off += R * NTOT * 2;        // unnormalized softmax wts
  float* Qp  = (float*)(ws + off); off += 4 * R * CH * 4;      // split-K partials
  u16*   Qb  = (u16*)(ws + off);   off += R * CH * 2;          // soft_nn bf16
  u16*   abf = (u16*)(ws + off);   off += (size_t)NTOT * CH * 2;
  u16*   bbf = (u16*)(ws + off);   off += (size_t)NTOT * CH * 2;
  u16*   att = (u16*)(ws + off);   off += (size_t)NTOT * CH * 2;  // a^T bf16
  u16*   btt = (u16*)(ws + off);   off += (size_t)NTOT * CH * 2;  // b^T bf16
  float* na  = (float*)(ws + off); off += (size_t)NTOT * 4;
  float* nb  = (float*)(ws + off); off += (size_t)NTOT * 4;
  float* dn  = (float*)(ws + off); off += R * 4;
  float* terms = (float*)(ws + off);

  cvt_norm_k<<<2 * NTOT, 64, 0, stream>>>(a, b, abf, bbf, na, nb);
  transpose2_k<<<dim3(CH / 32, NTOT / 32, 2), 256, 0, stream>>>(abf, bbf, att, btt);

  for (int dir = 0; dir < 2; ++dir) {
    const u16* X   = dir ? bbf : abf;
    const u16* Y   = dir ? abf : bbf;
    const u16* Yt  = dir ? att : btt;
    const float* nx  = dir ? nb : na;   // norms of this direction's emb_a (beta cols)
    const float* ny  = dir ? na : nb;   // norms of this direction's emb_b (softmax cols)
    const float* idx = dir ? idxb : idxa;

    for (size_t r0 = 0; r0 < NTOT; r0 += R) {
      // S = X_chunk . Y^T   (M=R, N=4096, K=256)
      gemm_nt_mfma<128, 128, 4, 4><<<dim3(NTOT / 128, R / 128, 1), 256, 0, stream>>>(
          X + r0 * CH, Y, S, CH, CH, NTOT, CH, 0);
      softmax_rows_k<<<R, 256, 0, stream>>>(S, ny, E, dn);
      // Qp[z] = E[:, z*1024:(z+1)*1024] . Yt[:, same]^T  (M=R, N=256, K=4096 split 4)
      gemm_nt_mfma<64, 64, 2, 2><<<dim3(CH / 64, R / 64, 4), 256, 0, stream>>>(
          E, Yt, Qp, NTOT, NTOT, CH, NTOT / 4, R * CH);
      reduce_q_k<<<R, 256, 0, stream>>>(Qp, dn, Qb, (int)R);
      // T = Q . X_full^T    (M=R, N=4096, K=256)
      gemm_nt_mfma<128, 128, 4, 4><<<dim3(NTOT / 128, R / 128, 1), 256, 0, stream>>>(
          Qb, X, S, CH, CH, NTOT, CH, 0);
      stats_rows_k<<<R, 256, 0, stream>>>(S, nx, idx, (int)r0, terms + dir * NTOT);
    }
  }
  final_reduce_k<<<1, 256, 0, stream>>>(terms, out);
}

// Round 3
// 177.937 us; speedup vs baseline: 10.0261x; 1.3617x over previous
//
#include <hip/hip_runtime.h>

#define NTOT 4096
#define CH 256
#define SCALE 0.0390625f   // 1/(256*0.1)
#define LAM 0.001f

typedef unsigned short u16;
typedef __attribute__((ext_vector_type(8))) short short8;   // 8 bf16 (4 VGPRs)
typedef __attribute__((ext_vector_type(4))) float floatx4;  // MFMA acc

__device__ __forceinline__ float wave_sum64(float v) {
  #pragma unroll
  for (int o = 32; o; o >>= 1) v += __shfl_down(v, o, 64);
  return v;
}
__device__ __forceinline__ u16 f2bf(float f) {  // round-to-nearest-even
  unsigned u = __float_as_uint(f);
  u += 0x7fffu + ((u >> 16) & 1u);
  return (u16)(u >> 16);
}
__device__ __forceinline__ float bf2f(u16 h) {
  return __uint_as_float(((unsigned)h) << 16);
}

// f32 -> bf16 for both inputs + row norms of the ROUNDED values (one wave/row).
__global__ __launch_bounds__(64) void cvt_norm_k(const float* __restrict__ a,
                                                 const float* __restrict__ b,
                                                 u16* __restrict__ ab, u16* __restrict__ bb,
                                                 float* __restrict__ na, float* __restrict__ nb) {
  int row = blockIdx.x;
  const float* src; u16* dst; float* nd;
  if (row < NTOT) { src = a; dst = ab; nd = na; }
  else { row -= NTOT; src = b; dst = bb; nd = nb; }
  const float4 v = *reinterpret_cast<const float4*>(src + (size_t)row * CH + threadIdx.x * 4);
  const u16 h0 = f2bf(v.x), h1 = f2bf(v.y), h2 = f2bf(v.z), h3 = f2bf(v.w);
  uint2 st;
  st.x = (unsigned)h0 | ((unsigned)h1 << 16);
  st.y = (unsigned)h2 | ((unsigned)h3 << 16);
  *reinterpret_cast<uint2*>(dst + (size_t)row * CH + threadIdx.x * 4) = st;
  const float f0 = bf2f(h0), f1 = bf2f(h1), f2 = bf2f(h2), f3 = bf2f(h3);
  float s = f0 * f0 + f1 * f1 + f2 * f2 + f3 * f3;
  s = wave_sum64(s);
  if (threadIdx.x == 0) nd[row] = s;
}

// [4096][256] -> [256][4096] bf16 transpose for both inputs (z selects a/b)
__global__ __launch_bounds__(256) void transpose2_k(const u16* __restrict__ ab,
                                                    const u16* __restrict__ bb,
                                                    u16* __restrict__ at, u16* __restrict__ bt) {
  const u16* __restrict__ src = blockIdx.z ? bb : ab;
  u16* __restrict__ dst = blockIdx.z ? bt : at;
  __shared__ u16 t[32][33];
  const int bx = blockIdx.x * 32, by = blockIdx.y * 32;
  const int lx = threadIdx.x & 31, ly = threadIdx.x >> 5;
  #pragma unroll
  for (int i = 0; i < 32; i += 8)
    t[ly + i][lx] = src[(size_t)(by + ly + i) * CH + bx + lx];
  __syncthreads();
  #pragma unroll
  for (int i = 0; i < 32; i += 8)
    dst[(size_t)(bx + ly + i) * NTOT + by + lx] = t[lx][ly + i];
}

// ---------------------------------------------------------------------------
// Fused phase-1 GEMM: acc = A_chunk . B^T (K=CH), then w = exp((2*acc-ny)*SCALE),
// E = bf16(w), per-row partial sums dnp[row][64] (32 col-blocks x 2 wave-halves).
// No row max needed: logits bounded (row-const ||x||^2 dropped; cancels in ratio).
__global__ __launch_bounds__(256, 2) void gemm_exp_k(const u16* __restrict__ A,
                                                     const u16* __restrict__ B,
                                                     const float* __restrict__ ny,
                                                     u16* __restrict__ E,
                                                     float* __restrict__ dnp) {
  __shared__ u16 As[128][64];
  __shared__ u16 Bs[128][64];
  const int tid = threadIdx.x, wid = tid >> 6, lane = tid & 63;
  const int bn = blockIdx.x * 128, bm = blockIdx.y * 128;
  const int wr = (wid >> 1) * 64, wc = (wid & 1) * 64;
  const int lr = lane & 15, lk = (lane >> 4) * 8;
  floatx4 acc[4][4] = {};
  for (int k0 = 0; k0 < CH; k0 += 64) {
    #pragma unroll
    for (int i = 0; i < 4; ++i) {
      const int lb = (wid + 4 * i) * 1024;
      const int r = (lb + lane * 16) >> 7;
      const int c = ((lb + lane * 16) & 127) >> 1;
      __builtin_amdgcn_global_load_lds(
          (const __attribute__((address_space(1))) void*)(A + (size_t)(bm + r) * CH + k0 + c),
          (__attribute__((address_space(3))) void*)((char*)&As[0][0] + lb), 16, 0, 0);
      __builtin_amdgcn_global_load_lds(
          (const __attribute__((address_space(1))) void*)(B + (size_t)(bn + r) * CH + k0 + c),
          (__attribute__((address_space(3))) void*)((char*)&Bs[0][0] + lb), 16, 0, 0);
    }
    __syncthreads();
    #pragma unroll
    for (int ks = 0; ks < 2; ++ks) {
      short8 af[4], bfr[4];
      #pragma unroll
      for (int m = 0; m < 4; ++m)
        af[m] = *reinterpret_cast<const short8*>(&As[wr + m * 16 + lr][ks * 32 + lk]);
      #pragma unroll
      for (int n = 0; n < 4; ++n)
        bfr[n] = *reinterpret_cast<const short8*>(&Bs[wc + n * 16 + lr][ks * 32 + lk]);
      #pragma unroll
      for (int m = 0; m < 4; ++m)
        #pragma unroll
        for (int n = 0; n < 4; ++n)
          acc[m][n] = __builtin_amdgcn_mfma_f32_16x16x32_bf16(af[m], bfr[n], acc[m][n], 0, 0, 0);
    }
    __syncthreads();
  }
  // epilogue: w = exp(logit), write bf16 E, accumulate per-row sums
  float nyv[4];
  #pragma unroll
  for (int n = 0; n < 4; ++n) nyv[n] = ny[bn + wc + n * 16 + lr];
  float rowsum[4][4] = {};
  #pragma unroll
  for (int m = 0; m < 4; ++m) {
    const int rowb = bm + wr + m * 16 + (lane >> 4) * 4;
    #pragma unroll
    for (int n = 0; n < 4; ++n) {
      const int col = bn + wc + n * 16 + lr;
      #pragma unroll
      for (int r = 0; r < 4; ++r) {
        const float w = __expf((2.f * acc[m][n][r] - nyv[n]) * SCALE);
        E[(size_t)(rowb + r) * NTOT + col] = f2bf(w);
        rowsum[m][r] += w;
      }
    }
  }
  #pragma unroll
  for (int m = 0; m < 4; ++m) {
    const int rowb = bm + wr + m * 16 + (lane >> 4) * 4;
    #pragma unroll
    for (int r = 0; r < 4; ++r) {
      float s = rowsum[m][r];
      #pragma unroll
      for (int o = 1; o < 16; o <<= 1) s += __shfl_xor(s, o, 64);
      if (lr == 0) dnp[(size_t)(rowb + r) * 64 + blockIdx.x * 2 + (wid & 1)] = s;
    }
  }
}

// ---------------------------------------------------------------------------
// Plain NT bf16 MFMA GEMM (used for Qp = E . Yt^T split-K).
template<int BM, int BN, int MF, int NF>
__global__ __launch_bounds__(256, 2) void gemm_nt_mfma(const u16* __restrict__ A,
                                                       const u16* __restrict__ B,
                                                       float* __restrict__ C,
                                                       int lda, int ldb, int ldc,
                                                       int kchunk, size_t cstride) {
  __shared__ u16 As[BM][64];
  __shared__ u16 Bs[BN][64];
  const int tid = threadIdx.x;
  const int wid = tid >> 6, lane = tid & 63;
  const int bn = blockIdx.x * BN, bm = blockIdx.y * BM;
  const int k0base = blockIdx.z * kchunk;
  C += (size_t)blockIdx.z * cstride;
  const int wr = (wid >> 1) * MF * 16;
  const int wc = (wid & 1) * NF * 16;
  const int lr = lane & 15;
  const int lk = (lane >> 4) * 8;
  floatx4 acc[MF][NF] = {};
  for (int kk = 0; kk < kchunk; kk += 64) {
    const int k0 = k0base + kk;
    #pragma unroll
    for (int i = 0; i < BM / 32; ++i) {
      const int lb = (wid + 4 * i) * 1024;
      const int r = (lb + lane * 16) >> 7;
      const int c = ((lb + lane * 16) & 127) >> 1;
      __builtin_amdgcn_global_load_lds(
          (const __attribute__((address_space(1))) void*)(A + (size_t)(bm + r) * lda + k0 + c),
          (__attribute__((address_space(3))) void*)((char*)&As[0][0] + lb), 16, 0, 0);
    }
    #pragma unroll
    for (int i = 0; i < BN / 32; ++i) {
      const int lb = (wid + 4 * i) * 1024;
      const int r = (lb + lane * 16) >> 7;
      const int c = ((lb + lane * 16) & 127) >> 1;
      __builtin_amdgcn_global_load_lds(
          (const __attribute__((address_space(1))) void*)(B + (size_t)(bn + r) * ldb + k0 + c),
          (__attribute__((address_space(3))) void*)((char*)&Bs[0][0] + lb), 16, 0, 0);
    }
    __syncthreads();
    #pragma unroll
    for (int ks = 0; ks < 2; ++ks) {
      short8 af[MF], bfr[NF];
      #pragma unroll
      for (int m = 0; m < MF; ++m)
        af[m] = *reinterpret_cast<const short8*>(&As[wr + m * 16 + lr][ks * 32 + lk]);
      #pragma unroll
      for (int n = 0; n < NF; ++n)
        bfr[n] = *reinterpret_cast<const short8*>(&Bs[wc + n * 16 + lr][ks * 32 + lk]);
      #pragma unroll
      for (int m = 0; m < MF; ++m)
        #pragma unroll
        for (int n = 0; n < NF; ++n)
          acc[m][n] = __builtin_amdgcn_mfma_f32_16x16x32_bf16(af[m], bfr[n], acc[m][n], 0, 0, 0);
    }
    __syncthreads();
  }
  #pragma unroll
  for (int m = 0; m < MF; ++m) {
    const int row = bm + wr + m * 16 + (lane >> 4) * 4;
    #pragma unroll
    for (int n = 0; n < NF; ++n) {
      const int col = bn + wc + n * 16 + lr;
      #pragma unroll
      for (int r = 0; r < 4; ++r)
        C[(size_t)(row + r) * ldc + col] = acc[m][n][r];
    }
  }
}

// Q = (sum of 4 split-K partials) / dn -> bf16. Block per row; dn = sum dnp[row][0..63].
__global__ __launch_bounds__(256) void reduce_q_k(const float* __restrict__ Qp,
                                                  const float* __restrict__ dnp,
                                                  u16* __restrict__ Qb, int R) {
  const int row = blockIdx.x, tid = threadIdx.x;
  __shared__ float sdn;
  if (tid < 64) {
    float s = dnp[(size_t)row * 64 + tid];
    s = wave_sum64(s);
    if (tid == 0) sdn = 1.0f / s;
  }
  __syncthreads();
  const float rdn = sdn;
  const size_t o = (size_t)row * CH + tid;
  const size_t st = (size_t)R * CH;
  const float q = (Qp[o] + Qp[o + st] + Qp[o + 2 * st] + Qp[o + 3 * st]) * rdn;
  Qb[o] = f2bf(q);
}

// ---------------------------------------------------------------------------
// Fused phase-2: T-tile = Qb . X^T (never materialized); w = exp((2T-nx)*SCALE);
// accumulate s0, s1=sum w*(idx-c), s2=sum w*(idx-c)^2 per row (c = idx[row],
// kills E[x^2]-pred^2 cancellation). Partials -> statsp[row][32] float4.
__global__ __launch_bounds__(256, 2) void flash_stats_k(const u16* __restrict__ Qb,
                                                        const u16* __restrict__ X,
                                                        const float* __restrict__ nx,
                                                        const float* __restrict__ idxc,
                                                        const float* __restrict__ idxr,
                                                        float4* __restrict__ statsp) {
  __shared__ u16 As[128][64];
  __shared__ u16 Bs[128][64];
  const int tid = threadIdx.x, wid = tid >> 6, lane = tid & 63;
  const int bm = blockIdx.y * 128;
  const int jbase = blockIdx.x * 256;          // jchunk = 256 (2 tiles of 128)
  const int wr = (wid >> 1) * 64, wc = (wid & 1) * 64;
  const int lr = lane & 15, lk = (lane >> 4) * 8;

  float cen[4][4];
  #pragma unroll
  for (int m = 0; m < 4; ++m) {
    const int rowb = bm + wr + m * 16 + (lane >> 4) * 4;
    #pragma unroll
    for (int r = 0; r < 4; ++r) cen[m][r] = idxr[rowb + r];
  }
  float s0[4][4] = {}, s1[4][4] = {}, s2[4][4] = {};

  for (int jt = 0; jt < 256; jt += 128) {
    const int bn = jbase + jt;
    floatx4 acc[4][4] = {};
    for (int k0 = 0; k0 < CH; k0 += 64) {
      #pragma unroll
      for (int i = 0; i < 4; ++i) {
        const int lb = (wid + 4 * i) * 1024;
        const int r = (lb + lane * 16) >> 7;
        const int c = ((lb + lane * 16) & 127) >> 1;
        __builtin_amdgcn_global_load_lds(
            (const __attribute__((address_space(1))) void*)(Qb + (size_t)(bm + r) * CH + k0 + c),
            (__attribute__((address_space(3))) void*)((char*)&As[0][0] + lb), 16, 0, 0);
        __builtin_amdgcn_global_load_lds(
            (const __attribute__((address_space(1))) void*)(X + (size_t)(bn + r) * CH + k0 + c),
            (__attribute__((address_space(3))) void*)((char*)&Bs[0][0] + lb), 16, 0, 0);
      }
      __syncthreads();
      #pragma unroll
      for (int ks = 0; ks < 2; ++ks) {
        short8 af[4], bfr[4];
        #pragma unroll
        for (int m = 0; m < 4; ++m)
          af[m] = *reinterpret_cast<const short8*>(&As[wr + m * 16 + lr][ks * 32 + lk]);
        #pragma unroll
        for (int n = 0; n < 4; ++n)
          bfr[n] = *reinterpret_cast<const short8*>(&Bs[wc + n * 16 + lr][ks * 32 + lk]);
        #pragma unroll
        for (int m = 0; m < 4; ++m)
          #pragma unroll
          for (int n = 0; n < 4; ++n)
            acc[m][n] = __builtin_amdgcn_mfma_f32_16x16x32_bf16(af[m], bfr[n], acc[m][n], 0, 0, 0);
      }
      __syncthreads();
    }
    // accumulate stats from this j-tile (T never written)
    #pragma unroll
    for (int n = 0; n < 4; ++n) {
      const int col = bn + wc + n * 16 + lr;
      const float nxv = nx[col];
      const float iv = idxc[col];
      #pragma unroll
      for (int m = 0; m < 4; ++m) {
        #pragma unroll
        for (int r = 0; r < 4; ++r) {
          const float w = __expf((2.f * acc[m][n][r] - nxv) * SCALE);
          const float d = iv - cen[m][r];
          s0[m][r] += w;
          s1[m][r] += w * d;
          s2[m][r] += w * d * d;
        }
      }
    }
  }
  // cross-lane reduce over the 16-lane col group; write partials
  #pragma unroll
  for (int m = 0; m < 4; ++m) {
    const int rowb = bm + wr + m * 16 + (lane >> 4) * 4;
    #pragma unroll
    for (int r = 0; r < 4; ++r) {
      float a = s0[m][r], b = s1[m][r], c = s2[m][r];
      #pragma unroll
      for (int o = 1; o < 16; o <<= 1) {
        a += __shfl_xor(a, o, 64);
        b += __shfl_xor(b, o, 64);
        c += __shfl_xor(c, o, 64);
      }
      if (lr == 0)
        statsp[(size_t)(rowb + r) * 32 + blockIdx.x * 2 + (wid & 1)] = make_float4(a, b, c, 0.f);
    }
  }
}

// per-row: combine 32 partials -> loss term. pred-c = S1/S0; var = S2/S0 - mu^2.
__global__ __launch_bounds__(256) void stats_combine_k(const float4* __restrict__ statsp,
                                                       float* __restrict__ terms) {
  const int row = blockIdx.x * 256 + threadIdx.x;   // 0..2*NTOT-1
  float S0 = 0.f, S1 = 0.f, S2 = 0.f;
  #pragma unroll
  for (int p = 0; p < 32; ++p) {
    const float4 v = statsp[(size_t)row * 32 + p];
    S0 += v.x; S1 += v.y; S2 += v.z;
  }
  const float mu = S1 / S0;
  const float var = S2 / S0 - mu * mu;
  terms[row] = mu * mu / var + LAM * logf(var);
}

__global__ __launch_bounds__(256) void final_reduce_k(const float* __restrict__ terms,
                                                      float* __restrict__ out) {
  float s = 0.f;
  for (int i = threadIdx.x; i < 2 * NTOT; i += 256) s += terms[i];
  __shared__ float red[4];
  s = wave_sum64(s);
  if ((threadIdx.x & 63) == 0) red[threadIdx.x >> 6] = s;
  __syncthreads();
  if (threadIdx.x == 0) out[0] = (red[0] + red[1] + red[2] + red[3]) * (1.0f / (2.0f * NTOT));
}

extern "C" void kernel_launch(void* const* d_in, const int* in_sizes, int n_in,
                              void* d_out, int out_size, void* d_ws, size_t ws_size,
                              hipStream_t stream) {
  const float* a    = (const float*)d_in[0];
  const float* b    = (const float*)d_in[1];
  const float* idxa = (const float*)d_in[2];
  const float* idxb = (const float*)d_in[3];
  float* out = (float*)d_out;
  char* ws = (char*)d_ws;

  auto need = [](size_t R) -> size_t {
    return R * NTOT * 2 + 4 * R * CH * 4 + R * CH * 2 + 4 * (size_t)NTOT * CH * 2 +
           2 * (size_t)NTOT * 4 + R * 64 * 4 + 2 * (size_t)NTOT * 32 * 16 +
           2 * (size_t)NTOT * 4;
  };
  size_t R = NTOT;                              // R=4096 needs ~63 MB
  while (R > 128 && need(R) > ws_size) R >>= 1;

  size_t off = 0;
  u16*    E    = (u16*)(ws + off);    off += R * NTOT * 2;
  float*  Qp   = (float*)(ws + off);  off += 4 * R * CH * 4;
  u16*    Qb   = (u16*)(ws + off);    off += R * CH * 2;
  u16*    abf  = (u16*)(ws + off);    off += (size_t)NTOT * CH * 2;
  u16*    bbf  = (u16*)(ws + off);    off += (size_t)NTOT * CH * 2;
  u16*    att  = (u16*)(ws + off);    off += (size_t)NTOT * CH * 2;
  u16*    btt  = (u16*)(ws + off);    off += (size_t)NTOT * CH * 2;
  float*  na   = (float*)(ws + off);  off += (size_t)NTOT * 4;
  float*  nb   = (float*)(ws + off);  off += (size_t)NTOT * 4;
  float*  dnp  = (float*)(ws + off);  off += R * 64 * 4;
  float4* stp  = (float4*)(ws + off); off += 2 * (size_t)NTOT * 32 * 16;
  float*  terms = (float*)(ws + off);

  cvt_norm_k<<<2 * NTOT, 64, 0, stream>>>(a, b, abf, bbf, na, nb);
  transpose2_k<<<dim3(CH / 32, NTOT / 32, 2), 256, 0, stream>>>(abf, bbf, att, btt);

  for (int dir = 0; dir < 2; ++dir) {
    const u16* X   = dir ? bbf : abf;
    const u16* Y   = dir ? abf : bbf;
    const u16* Yt  = dir ? att : btt;
    const float* nx  = dir ? nb : na;
    const float* ny  = dir ? na : nb;
    const float* idx = dir ? idxb : idxa;

    for (size_t r0 = 0; r0 < NTOT; r0 += R) {
      // E = exp(softmax logits), dnp = partial row sums   (S never materialized)
      gemm_exp_k<<<dim3(NTOT / 128, R / 128), 256, 0, stream>>>(
          X + r0 * CH, Y, ny, E, dnp);
      // Qp[z] = E[:, z*1024:+1024] . Yt[:, same]^T  (split-K 4)
      gemm_nt_mfma<128, 128, 4, 4><<<dim3(CH / 128, R / 128, 4), 256, 0, stream>>>(
          E, Yt, Qp, NTOT, NTOT, CH, NTOT / 4, R * CH);
      reduce_q_k<<<R, 256, 0, stream>>>(Qp, dnp, Qb, (int)R);
      // fused T-GEMM + beta-softmax stats  (T never materialized)
      flash_stats_k<<<dim3(16, R / 128), 256, 0, stream>>>(
          Qb, X, nx, idx, idx + r0, stp + ((size_t)dir * NTOT + r0) * 32);
    }
  }
  stats_combine_k<<<2 * NTOT / 256, 256, 0, stream>>>(stp, terms);
  final_reduce_k<<<1, 256, 0, stream>>>(terms, out);
}

// Round 4
// 153.176 us; speedup vs baseline: 11.6468x; 1.1616x over previous
//
#include <hip/hip_runtime.h>

#define NTOT 4096
#define CH 256
#define SCALE 0.0390625f   // 1/(256*0.1)
#define LAM 0.001f

typedef unsigned short u16;
typedef __attribute__((ext_vector_type(8))) short short8;   // 8 bf16 (4 VGPRs)
typedef __attribute__((ext_vector_type(4))) float floatx4;  // MFMA acc

__device__ __forceinline__ float wave_sum64(float v) {
  #pragma unroll
  for (int o = 32; o; o >>= 1) v += __shfl_down(v, o, 64);
  return v;
}
__device__ __forceinline__ u16 f2bf(float f) {  // round-to-nearest-even
  unsigned u = __float_as_uint(f);
  u += 0x7fffu + ((u >> 16) & 1u);
  return (u16)(u >> 16);
}
__device__ __forceinline__ float bf2f(u16 h) {
  return __uint_as_float(((unsigned)h) << 16);
}
__device__ __forceinline__ void gload_lds(const u16* g, void* l) {
  __builtin_amdgcn_global_load_lds((const __attribute__((address_space(1))) void*)g,
                                   (__attribute__((address_space(3))) void*)l, 16, 0, 0);
}

// f32 -> bf16 for both inputs + row norms of the ROUNDED values (one wave/row).
__global__ __launch_bounds__(64) void cvt_norm_k(const float* __restrict__ a,
                                                 const float* __restrict__ b,
                                                 u16* __restrict__ ab, u16* __restrict__ bb,
                                                 float* __restrict__ na, float* __restrict__ nb) {
  int row = blockIdx.x;
  const float* src; u16* dst; float* nd;
  if (row < NTOT) { src = a; dst = ab; nd = na; }
  else { row -= NTOT; src = b; dst = bb; nd = nb; }
  const float4 v = *reinterpret_cast<const float4*>(src + (size_t)row * CH + threadIdx.x * 4);
  const u16 h0 = f2bf(v.x), h1 = f2bf(v.y), h2 = f2bf(v.z), h3 = f2bf(v.w);
  uint2 st;
  st.x = (unsigned)h0 | ((unsigned)h1 << 16);
  st.y = (unsigned)h2 | ((unsigned)h3 << 16);
  *reinterpret_cast<uint2*>(dst + (size_t)row * CH + threadIdx.x * 4) = st;
  const float f0 = bf2f(h0), f1 = bf2f(h1), f2 = bf2f(h2), f3 = bf2f(h3);
  float s = f0 * f0 + f1 * f1 + f2 * f2 + f3 * f3;
  s = wave_sum64(s);
  if (threadIdx.x == 0) nd[row] = s;
}

// [4096][256] -> [256][4096] bf16 transpose for both inputs (z selects a/b)
__global__ __launch_bounds__(256) void transpose2_k(const u16* __restrict__ ab,
                                                    const u16* __restrict__ bb,
                                                    u16* __restrict__ at, u16* __restrict__ bt) {
  const u16* __restrict__ src = blockIdx.z ? bb : ab;
  u16* __restrict__ dst = blockIdx.z ? bt : at;
  __shared__ u16 t[32][33];
  const int bx = blockIdx.x * 32, by = blockIdx.y * 32;
  const int lx = threadIdx.x & 31, ly = threadIdx.x >> 5;
  #pragma unroll
  for (int i = 0; i < 32; i += 8)
    t[ly + i][lx] = src[(size_t)(by + ly + i) * CH + bx + lx];
  __syncthreads();
  #pragma unroll
  for (int i = 0; i < 32; i += 8)
    dst[(size_t)(bx + ly + i) * NTOT + by + lx] = t[lx][ly + i];
}

// ---------------------------------------------------------------------------
// Phase-1 GEMM fused with exp: E = bf16(exp((2*X.Y^T - ny)*SCALE)), per-row
// partial sums dnp. Both dirs via blockIdx.z. 2-phase pipelined staging.
__global__ __launch_bounds__(256, 2) void gemm_exp_k(const u16* __restrict__ abf,
                                                     const u16* __restrict__ bbf,
                                                     const float* __restrict__ na,
                                                     const float* __restrict__ nb,
                                                     u16* __restrict__ E,
                                                     float* __restrict__ dnp) {
  const int dir = blockIdx.z;
  const u16* __restrict__ A = dir ? bbf : abf;
  const u16* __restrict__ B = dir ? abf : bbf;
  const float* __restrict__ ny = dir ? na : nb;
  E += (size_t)dir * NTOT * NTOT;
  dnp += (size_t)dir * NTOT * 64;

  __shared__ u16 As[2][128][64];
  __shared__ u16 Bs[2][128][64];
  const int tid = threadIdx.x, wid = tid >> 6, lane = tid & 63;
  const int bn = blockIdx.x * 128, bm = blockIdx.y * 128;
  const int wr = (wid >> 1) * 64, wc = (wid & 1) * 64;
  const int lr = lane & 15, lk = (lane >> 4) * 8;

  auto stage = [&](int t, int bi) {
    const int k0 = t * 64;
    #pragma unroll
    for (int i = 0; i < 4; ++i) {
      const int lb = (wid + 4 * i) * 1024;
      const int r = (lb + lane * 16) >> 7;
      const int c = ((lb + lane * 16) & 127) >> 1;
      gload_lds(A + (size_t)(bm + r) * CH + k0 + c, (char*)&As[bi][0][0] + lb);
      gload_lds(B + (size_t)(bn + r) * CH + k0 + c, (char*)&Bs[bi][0][0] + lb);
    }
  };

  floatx4 acc[4][4] = {};
  stage(0, 0);
  asm volatile("s_waitcnt vmcnt(0)" ::: "memory");
  __builtin_amdgcn_s_barrier();
  #pragma unroll
  for (int t = 0; t < 4; ++t) {
    if (t < 3) stage(t + 1, (t + 1) & 1);
    const int bi = t & 1;
    #pragma unroll
    for (int ks = 0; ks < 2; ++ks) {
      short8 af[4], bfr[4];
      #pragma unroll
      for (int m = 0; m < 4; ++m)
        af[m] = *reinterpret_cast<const short8*>(&As[bi][wr + m * 16 + lr][ks * 32 + lk]);
      #pragma unroll
      for (int n = 0; n < 4; ++n)
        bfr[n] = *reinterpret_cast<const short8*>(&Bs[bi][wc + n * 16 + lr][ks * 32 + lk]);
      #pragma unroll
      for (int m = 0; m < 4; ++m)
        #pragma unroll
        for (int n = 0; n < 4; ++n)
          acc[m][n] = __builtin_amdgcn_mfma_f32_16x16x32_bf16(af[m], bfr[n], acc[m][n], 0, 0, 0);
    }
    if (t < 3) {
      asm volatile("s_waitcnt vmcnt(0)" ::: "memory");
      __builtin_amdgcn_s_barrier();
    }
  }
  // epilogue: w = exp(logit), write bf16 E, accumulate per-row sums
  float nyv[4];
  #pragma unroll
  for (int n = 0; n < 4; ++n) nyv[n] = ny[bn + wc + n * 16 + lr];
  float rowsum[4][4] = {};
  #pragma unroll
  for (int m = 0; m < 4; ++m) {
    const int rowb = bm + wr + m * 16 + (lane >> 4) * 4;
    #pragma unroll
    for (int n = 0; n < 4; ++n) {
      const int col = bn + wc + n * 16 + lr;
      #pragma unroll
      for (int r = 0; r < 4; ++r) {
        const float w = __expf((2.f * acc[m][n][r] - nyv[n]) * SCALE);
        E[(size_t)(rowb + r) * NTOT + col] = f2bf(w);
        rowsum[m][r] += w;
      }
    }
  }
  #pragma unroll
  for (int m = 0; m < 4; ++m) {
    const int rowb = bm + wr + m * 16 + (lane >> 4) * 4;
    #pragma unroll
    for (int r = 0; r < 4; ++r) {
      float s = rowsum[m][r];
      #pragma unroll
      for (int o = 1; o < 16; o <<= 1) s += __shfl_xor(s, o, 64);
      if (lr == 0) dnp[(size_t)(rowb + r) * 64 + blockIdx.x * 2 + (wid & 1)] = s;
    }
  }
}

// ---------------------------------------------------------------------------
// Qp = E . Yt^T, split-K 4, both dirs. z = dir*4 + kz. 2-phase pipelined.
__global__ __launch_bounds__(256, 2) void gemm_qp_k(const u16* __restrict__ E,
                                                    const u16* __restrict__ att,
                                                    const u16* __restrict__ btt,
                                                    float* __restrict__ Qp) {
  const int dir = blockIdx.z >> 2, kz = blockIdx.z & 3;
  const u16* __restrict__ A = E + (size_t)dir * NTOT * NTOT;
  const u16* __restrict__ B = dir ? att : btt;
  float* __restrict__ C = Qp + (size_t)dir * 4 * NTOT * CH + (size_t)kz * NTOT * CH;
  const int k0base = kz * (NTOT / 4);

  __shared__ u16 As[2][128][64];
  __shared__ u16 Bs[2][128][64];
  const int tid = threadIdx.x, wid = tid >> 6, lane = tid & 63;
  const int bn = blockIdx.x * 128, bm = blockIdx.y * 128;
  const int wr = (wid >> 1) * 64, wc = (wid & 1) * 64;
  const int lr = lane & 15, lk = (lane >> 4) * 8;

  auto stage = [&](int t, int bi) {
    const int k0 = k0base + t * 64;
    #pragma unroll
    for (int i = 0; i < 4; ++i) {
      const int lb = (wid + 4 * i) * 1024;
      const int r = (lb + lane * 16) >> 7;
      const int c = ((lb + lane * 16) & 127) >> 1;
      gload_lds(A + (size_t)(bm + r) * NTOT + k0 + c, (char*)&As[bi][0][0] + lb);
      gload_lds(B + (size_t)(bn + r) * NTOT + k0 + c, (char*)&Bs[bi][0][0] + lb);
    }
  };

  floatx4 acc[4][4] = {};
  stage(0, 0);
  asm volatile("s_waitcnt vmcnt(0)" ::: "memory");
  __builtin_amdgcn_s_barrier();
  for (int t = 0; t < 16; ++t) {
    if (t < 15) stage(t + 1, (t + 1) & 1);
    const int bi = t & 1;
    #pragma unroll
    for (int ks = 0; ks < 2; ++ks) {
      short8 af[4], bfr[4];
      #pragma unroll
      for (int m = 0; m < 4; ++m)
        af[m] = *reinterpret_cast<const short8*>(&As[bi][wr + m * 16 + lr][ks * 32 + lk]);
      #pragma unroll
      for (int n = 0; n < 4; ++n)
        bfr[n] = *reinterpret_cast<const short8*>(&Bs[bi][wc + n * 16 + lr][ks * 32 + lk]);
      #pragma unroll
      for (int m = 0; m < 4; ++m)
        #pragma unroll
        for (int n = 0; n < 4; ++n)
          acc[m][n] = __builtin_amdgcn_mfma_f32_16x16x32_bf16(af[m], bfr[n], acc[m][n], 0, 0, 0);
    }
    asm volatile("s_waitcnt vmcnt(0)" ::: "memory");
    __builtin_amdgcn_s_barrier();
  }
  #pragma unroll
  for (int m = 0; m < 4; ++m) {
    const int row = bm + wr + m * 16 + (lane >> 4) * 4;
    #pragma unroll
    for (int n = 0; n < 4; ++n) {
      const int col = bn + wc + n * 16 + lr;
      #pragma unroll
      for (int r = 0; r < 4; ++r)
        C[(size_t)(row + r) * CH + col] = acc[m][n][r];
    }
  }
}

// Q = (sum of 4 split-K partials) / dn -> bf16. Block per row; both dirs via z.
__global__ __launch_bounds__(256) void reduce_q_k(const float* __restrict__ Qp,
                                                  const float* __restrict__ dnp,
                                                  u16* __restrict__ Qb) {
  const int dir = blockIdx.z;
  Qp += (size_t)dir * 4 * NTOT * CH;
  dnp += (size_t)dir * NTOT * 64;
  Qb += (size_t)dir * NTOT * CH;
  const int row = blockIdx.x, tid = threadIdx.x;
  __shared__ float sdn;
  if (tid < 64) {
    float s = dnp[(size_t)row * 64 + tid];
    s = wave_sum64(s);
    if (tid == 0) sdn = 1.0f / s;
  }
  __syncthreads();
  const float rdn = sdn;
  const size_t o = (size_t)row * CH + tid;
  const size_t st = (size_t)NTOT * CH;
  const float q = (Qp[o] + Qp[o + st] + Qp[o + 2 * st] + Qp[o + 3 * st]) * rdn;
  Qb[o] = f2bf(q);
}

// ---------------------------------------------------------------------------
// Phase-2 flash: T-tile = Qb . X^T (never materialized); w = exp((2T-nx)*SCALE);
// accumulate s0, s1 = sum w*(idx-c), s2 = sum w*(idx-c)^2 per row. Both dirs.
// Flattened 8-iter (2 j-tiles x 4 K-steps) 2-phase pipelined loop.
__global__ __launch_bounds__(256, 2) void flash_stats_k(const u16* __restrict__ Qball,
                                                        const u16* __restrict__ abf,
                                                        const u16* __restrict__ bbf,
                                                        const float* __restrict__ na,
                                                        const float* __restrict__ nb,
                                                        const float* __restrict__ idxa,
                                                        const float* __restrict__ idxb,
                                                        float4* __restrict__ statsp) {
  const int dir = blockIdx.z;
  const u16* __restrict__ Qb = Qball + (size_t)dir * NTOT * CH;
  const u16* __restrict__ X = dir ? bbf : abf;
  const float* __restrict__ nx = dir ? nb : na;
  const float* __restrict__ idx = dir ? idxb : idxa;
  statsp += (size_t)dir * NTOT * 32;

  __shared__ u16 As[2][128][64];
  __shared__ u16 Bs[2][128][64];
  const int tid = threadIdx.x, wid = tid >> 6, lane = tid & 63;
  const int bm = blockIdx.y * 128;
  const int jbase = blockIdx.x * 256;
  const int wr = (wid >> 1) * 64, wc = (wid & 1) * 64;
  const int lr = lane & 15, lk = (lane >> 4) * 8;

  auto stage = [&](int t, int bi) {
    const int k0 = (t & 3) * 64;
    const int bn = jbase + (t >> 2) * 128;
    #pragma unroll
    for (int i = 0; i < 4; ++i) {
      const int lb = (wid + 4 * i) * 1024;
      const int r = (lb + lane * 16) >> 7;
      const int c = ((lb + lane * 16) & 127) >> 1;
      gload_lds(Qb + (size_t)(bm + r) * CH + k0 + c, (char*)&As[bi][0][0] + lb);
      gload_lds(X + (size_t)(bn + r) * CH + k0 + c, (char*)&Bs[bi][0][0] + lb);
    }
  };

  float cen[4][4];
  #pragma unroll
  for (int m = 0; m < 4; ++m) {
    const int rowb = bm + wr + m * 16 + (lane >> 4) * 4;
    #pragma unroll
    for (int r = 0; r < 4; ++r) cen[m][r] = idx[rowb + r];
  }
  float s0[4][4] = {}, s1[4][4] = {}, s2[4][4] = {};
  floatx4 acc[4][4] = {};

  stage(0, 0);
  asm volatile("s_waitcnt vmcnt(0)" ::: "memory");
  __builtin_amdgcn_s_barrier();
  #pragma unroll
  for (int t = 0; t < 8; ++t) {
    if (t < 7) stage(t + 1, (t + 1) & 1);
    const int bi = t & 1;
    #pragma unroll
    for (int ks = 0; ks < 2; ++ks) {
      short8 af[4], bfr[4];
      #pragma unroll
      for (int m = 0; m < 4; ++m)
        af[m] = *reinterpret_cast<const short8*>(&As[bi][wr + m * 16 + lr][ks * 32 + lk]);
      #pragma unroll
      for (int n = 0; n < 4; ++n)
        bfr[n] = *reinterpret_cast<const short8*>(&Bs[bi][wc + n * 16 + lr][ks * 32 + lk]);
      #pragma unroll
      for (int m = 0; m < 4; ++m)
        #pragma unroll
        for (int n = 0; n < 4; ++n)
          acc[m][n] = __builtin_amdgcn_mfma_f32_16x16x32_bf16(af[m], bfr[n], acc[m][n], 0, 0, 0);
    }
    if ((t & 3) == 3) {  // end of a j-tile: fold stats, reset acc
      const int bn = jbase + (t >> 2) * 128;
      #pragma unroll
      for (int n = 0; n < 4; ++n) {
        const int col = bn + wc + n * 16 + lr;
        const float nxv = nx[col];
        const float iv = idx[col];
        #pragma unroll
        for (int m = 0; m < 4; ++m) {
          #pragma unroll
          for (int r = 0; r < 4; ++r) {
            const float w = __expf((2.f * acc[m][n][r] - nxv) * SCALE);
            const float d = iv - cen[m][r];
            s0[m][r] += w;
            s1[m][r] += w * d;
            s2[m][r] += w * d * d;
            acc[m][n][r] = 0.f;
          }
        }
      }
    }
    if (t < 7) {
      asm volatile("s_waitcnt vmcnt(0)" ::: "memory");
      __builtin_amdgcn_s_barrier();
    }
  }
  #pragma unroll
  for (int m = 0; m < 4; ++m) {
    const int rowb = bm + wr + m * 16 + (lane >> 4) * 4;
    #pragma unroll
    for (int r = 0; r < 4; ++r) {
      float a = s0[m][r], b = s1[m][r], c = s2[m][r];
      #pragma unroll
      for (int o = 1; o < 16; o <<= 1) {
        a += __shfl_xor(a, o, 64);
        b += __shfl_xor(b, o, 64);
        c += __shfl_xor(c, o, 64);
      }
      if (lr == 0)
        statsp[(size_t)(rowb + r) * 32 + blockIdx.x * 2 + (wid & 1)] = make_float4(a, b, c, 0.f);
    }
  }
}

// per-row: combine 32 partials -> loss term. mu = S1/S0; var = S2/S0 - mu^2.
__global__ __launch_bounds__(256) void stats_combine_k(const float4* __restrict__ statsp,
                                                       float* __restrict__ terms) {
  const int row = blockIdx.x * 256 + threadIdx.x;   // 0..2*NTOT-1
  float S0 = 0.f, S1 = 0.f, S2 = 0.f;
  #pragma unroll
  for (int p = 0; p < 32; ++p) {
    const float4 v = statsp[(size_t)row * 32 + p];
    S0 += v.x; S1 += v.y; S2 += v.z;
  }
  const float mu = S1 / S0;
  const float var = S2 / S0 - mu * mu;
  terms[row] = mu * mu / var + LAM * logf(var);
}

__global__ __launch_bounds__(256) void final_reduce_k(const float* __restrict__ terms,
                                                      float* __restrict__ out) {
  float s = 0.f;
  for (int i = threadIdx.x; i < 2 * NTOT; i += 256) s += terms[i];
  __shared__ float red[4];
  s = wave_sum64(s);
  if ((threadIdx.x & 63) == 0) red[threadIdx.x >> 6] = s;
  __syncthreads();
  if (threadIdx.x == 0) out[0] = (red[0] + red[1] + red[2] + red[3]) * (1.0f / (2.0f * NTOT));
}

extern "C" void kernel_launch(void* const* d_in, const int* in_sizes, int n_in,
                              void* d_out, int out_size, void* d_ws, size_t ws_size,
                              hipStream_t stream) {
  const float* a    = (const float*)d_in[0];
  const float* b    = (const float*)d_in[1];
  const float* idxa = (const float*)d_in[2];
  const float* idxb = (const float*)d_in[3];
  float* out = (float*)d_out;
  char* ws = (char*)d_ws;

  size_t off = 0;
  u16*    E    = (u16*)(ws + off);    off += 2 * (size_t)NTOT * NTOT * 2;   // 64 MB
  float*  Qp   = (float*)(ws + off);  off += 2 * 4 * (size_t)NTOT * CH * 4; // 32 MB
  u16*    Qb   = (u16*)(ws + off);    off += 2 * (size_t)NTOT * CH * 2;     // 4 MB
  u16*    abf  = (u16*)(ws + off);    off += (size_t)NTOT * CH * 2;
  u16*    bbf  = (u16*)(ws + off);    off += (size_t)NTOT * CH * 2;
  u16*    att  = (u16*)(ws + off);    off += (size_t)NTOT * CH * 2;
  u16*    btt  = (u16*)(ws + off);    off += (size_t)NTOT * CH * 2;
  float*  na   = (float*)(ws + off);  off += (size_t)NTOT * 4;
  float*  nb   = (float*)(ws + off);  off += (size_t)NTOT * 4;
  float*  dnp  = (float*)(ws + off);  off += 2 * (size_t)NTOT * 64 * 4;     // 2 MB
  float4* stp  = (float4*)(ws + off); off += 2 * (size_t)NTOT * 32 * 16;    // 4 MB
  float*  terms = (float*)(ws + off);

  cvt_norm_k<<<2 * NTOT, 64, 0, stream>>>(a, b, abf, bbf, na, nb);
  transpose2_k<<<dim3(CH / 32, NTOT / 32, 2), 256, 0, stream>>>(abf, bbf, att, btt);
  gemm_exp_k<<<dim3(NTOT / 128, NTOT / 128, 2), 256, 0, stream>>>(abf, bbf, na, nb, E, dnp);
  gemm_qp_k<<<dim3(CH / 128, NTOT / 128, 8), 256, 0, stream>>>(E, att, btt, Qp);
  reduce_q_k<<<dim3(NTOT, 1, 2), 256, 0, stream>>>(Qp, dnp, Qb);
  flash_stats_k<<<dim3(16, NTOT / 128, 2), 256, 0, stream>>>(Qb, abf, bbf, na, nb,
                                                             idxa, idxb, stp);
  stats_combine_k<<<2 * NTOT / 256, 256, 0, stream>>>(stp, terms);
  final_reduce_k<<<1, 256, 0, stream>>>(terms, out);
}